// Round 1
// baseline (699.274 us; speedup 1.0000x reference)
//
#include <hip/hip_runtime.h>

// Dequant: groups of 32 4-bit values packed as 17 int32 words/group
// (16 data words, low byte = two nibbles; word 16 = biased log2 scale).
//
// v2: LDS-staged reads.
// v1 issued 3 scalar dword loads/thread at a 17-word group stride: each
// wave-level load touched ~9 cache lines using only half of each (4 B/lane
// per instruction) -> read path capped the kernel at ~2.45 TB/s.
// v2 stages 256 whole groups (17,408 B, 16B-aligned, exactly 17 KiB-chunks)
// per 256-thread block into LDS via global_load_lds dwordx4 (1 KiB per
// wave-instruction, fully coalesced, no VGPR round-trip), then computes from
// LDS and stores coalesced float4 as before.
// LDS tile reads have <=4-way bank conflicts from the 17-word stride; at
// ~16 ds-instructions per 1.5 KB of HBM traffic this is far off the
// critical path. 17.4 KB LDS -> still 8 blocks/CU; inter-block overlap
// hides the stage->compute barrier.

constexpr int kGroupSize = 32;
constexpr int kPGS = kGroupSize / 2 + 1;              // 17 words per packed group

constexpr int kBlock = 256;
constexpr int kGroupsPerBlock = 256;
constexpr int kTileWords = kGroupsPerBlock * kPGS;    // 4352 words = 17,408 B
constexpr int kVec4PerBlock = kGroupsPerBlock * kGroupSize / 4;  // 2048 float4
constexpr int kChunkWords = 256;                      // 64 lanes * 16 B = 1 KiB
constexpr int kChunks = kTileWords / kChunkWords;     // 17 (exact)

__global__ __launch_bounds__(kBlock) void dequant_mxfp4_lds_kernel(
    const int* __restrict__ packed,
    const int* __restrict__ ebits_p,
    const int* __restrict__ mbits_p,
    float* __restrict__ out)
{
    __shared__ int tile[kTileWords];

    const int t    = threadIdx.x;
    const int wave = t >> 6;
    const int lane = t & 63;

    const int* gsrc = packed + (size_t)blockIdx.x * kTileWords;

    // ---- stage: global -> LDS, 1 KiB per wave-call, 17 calls/block ----
    // LDS dest is wave-uniform base; HW writes lane i at base + i*16.
    // Global src carries the per-lane offset. Linear both sides (rule #21).
#pragma unroll
    for (int k = 0; k < 5; ++k) {
        const int c = k * 4 + wave;                   // wave-uniform chunk id
        if (c < kChunks) {
            const int* g = gsrc + c * kChunkWords + lane * 4;
            __builtin_amdgcn_global_load_lds(
                (const __attribute__((address_space(1))) int*)g,
                (__attribute__((address_space(3))) int*)&tile[c * kChunkWords],
                16 /*bytes: literal*/, 0, 0);
        }
    }

    // Uniform scalar params (s_load; overlaps the staging latency).
    const int ebits = ebits_p[0];
    const int mbits = mbits_p[0];
    const float clamp_max = (float)(1 << ((1 << ebits) - 1));           // 8
    const float inv_max   = 1.0f / (clamp_max * (2.0f - exp2f((float)(-mbits))));  // 1/12

    __syncthreads();   // drains vmcnt -> tile complete

    float4* outv = reinterpret_cast<float4*>(out) + (size_t)blockIdx.x * kVec4PerBlock;

    // ---- compute: 8 float4 outputs/thread, coalesced dwordx4 stores ----
#pragma unroll
    for (int k = 0; k < kVec4PerBlock / kBlock; ++k) {
        const int v    = t + kBlock * k;              // float4 index in tile
        const int g    = v >> 3;
        const int b0   = (v & 7) * 2;
        const int base = g * kPGS;

        const int w0 = tile[base + b0];
        const int w1 = tile[base + b0 + 1];
        const int s  = tile[base + kGroupSize / 2];   // scale word (8-lane bcast)

        int e = s - 127;
        e = min(max(e, -126), 127);
        const float coef = ldexpf(1.0f, e) * inv_max; // 2^e / max_val

        float4 r;                                     // same math as v1 (verified)
        r.x = ((float)(w0 & 15)        - clamp_max) * coef;
        r.y = ((float)((w0 >> 4) & 15) - clamp_max) * coef;
        r.z = ((float)(w1 & 15)        - clamp_max) * coef;
        r.w = ((float)((w1 >> 4) & 15) - clamp_max) * coef;

        outv[v] = r;
    }
}

// Scalar tail fallback (v1 body). Not dispatched at the bench shape
// (33,554,432 float4 = 16384 full blocks exactly); kept for robustness.
__global__ __launch_bounds__(256) void dequant_mxfp4_tail_kernel(
    const int* __restrict__ packed,
    const int* __restrict__ ebits_p,
    const int* __restrict__ mbits_p,
    float* __restrict__ out,
    int v_begin, int n_vec4)
{
    int v = v_begin + blockIdx.x * 256 + threadIdx.x;
    if (v >= n_vec4) return;

    const int ebits = ebits_p[0];
    const int mbits = mbits_p[0];
    const float clamp_max = (float)(1 << ((1 << ebits) - 1));
    const float inv_max   = 1.0f / (clamp_max * (2.0f - exp2f((float)(-mbits))));

    int g  = v >> 3;
    int b0 = (v & 7) * 2;
    int base = g * kPGS;

    int w0 = packed[base + b0];
    int w1 = packed[base + b0 + 1];
    int s  = packed[base + kGroupSize / 2];

    int e = s - 127;
    e = min(max(e, -126), 127);
    float coef = ldexpf(1.0f, e) * inv_max;

    float4 r;
    r.x = ((float)(w0 & 15)        - clamp_max) * coef;
    r.y = ((float)((w0 >> 4) & 15) - clamp_max) * coef;
    r.z = ((float)(w1 & 15)        - clamp_max) * coef;
    r.w = ((float)((w1 >> 4) & 15) - clamp_max) * coef;

    reinterpret_cast<float4*>(out)[v] = r;
}

extern "C" void kernel_launch(void* const* d_in, const int* in_sizes, int n_in,
                              void* d_out, int out_size, void* d_ws, size_t ws_size,
                              hipStream_t stream) {
    const int* packed  = (const int*)d_in[0];
    // d_in[1] = group_size (structural, =32; packing geometry hardcoded)
    const int* ebits_p = (const int*)d_in[2];
    const int* mbits_p = (const int*)d_in[3];
    float* out = (float*)d_out;

    const int n_vec4 = out_size / 4;                  // 33,554,432 float4s
    const int n_full = n_vec4 / kVec4PerBlock;        // 16,384 blocks
    const int tail   = n_vec4 - n_full * kVec4PerBlock;

    if (n_full > 0) {
        dequant_mxfp4_lds_kernel<<<n_full, kBlock, 0, stream>>>(
            packed, ebits_p, mbits_p, out);
    }
    if (tail > 0) {
        const int tgrid = (tail + 255) / 256;
        dequant_mxfp4_tail_kernel<<<tgrid, 256, 0, stream>>>(
            packed, ebits_p, mbits_p, out, n_full * kVec4PerBlock, n_vec4);
    }
}